// Round 2
// baseline (479.080 us; speedup 1.0000x reference)
//
#include <hip/hip_runtime.h>
#include <math.h>

#define C_CLS 4
#define D_HALF 512
#define D4 128      // D_HALF / 4
#define DFEAT 1024
#define BB 32

// ---------------------------------------------------------------------------
// Kernel 1: per-(b, class) label counts for both label tensors.
// grid (B, 2): y==0 -> frame_label (len T), y==1 -> frame_tlabel (len U)
// cnt layout: [2][B][C_CLS] floats. Register histogram -> 4 LDS atomics/thread.
// ---------------------------------------------------------------------------
__global__ void count_kernel(const int* __restrict__ fl, const int* __restrict__ ftl,
                             int T, int U, float* __restrict__ cnt) {
    int b = blockIdx.x;
    int which = blockIdx.y;
    const int* lab = (which == 0) ? (fl + (size_t)b * T) : (ftl + (size_t)b * U);
    int n = (which == 0) ? T : U;
    __shared__ int h[C_CLS];
    if (threadIdx.x < C_CLS) h[threadIdx.x] = 0;
    __syncthreads();
    int h0 = 0, h1 = 0, h2 = 0, h3 = 0;
    for (int i = threadIdx.x; i < n; i += blockDim.x) {
        int c = lab[i];
        h0 += (c == 0); h1 += (c == 1); h2 += (c == 2); h3 += (c == 3);
    }
    if (h0) atomicAdd(&h[0], h0);
    if (h1) atomicAdd(&h[1], h1);
    if (h2) atomicAdd(&h[2], h2);
    if (h3) atomicAdd(&h[3], h3);
    __syncthreads();
    if (threadIdx.x < C_CLS)
        cnt[((size_t)which * gridDim.x + b) * C_CLS + threadIdx.x] = (float)h[threadIdx.x];
}

// ---------------------------------------------------------------------------
// Kernel 2: fused masked segmented sums over enc (B*SE blocks) + pred
// (B*SP blocks), 1-D grid. block 256: tx = float4 column (0..127), ty = t
// parity. partial layout: [B][splits][C_CLS][D_HALF] floats.
// High split counts (SE=64 -> 2048 enc blocks) give 32 waves/CU for latency
// hiding; round-1 run at SE=16 was latency-bound at 2 waves/SIMD.
// ---------------------------------------------------------------------------
__global__ void masked_sum_fused(const float* __restrict__ enc, const float* __restrict__ pred,
                                 const int* __restrict__ fl, const int* __restrict__ ftl,
                                 float* __restrict__ enc_part, float* __restrict__ pred_part,
                                 int T, int U, int SE, int SP) {
    int bid = blockIdx.x;
    const float* x; const int* labels; float* partial;
    int Tlen, splits, b, s;
    if (bid < BB * SE) {
        x = enc; labels = fl; partial = enc_part; Tlen = T; splits = SE;
        b = bid / SE; s = bid % SE;
    } else {
        int idx = bid - BB * SE;
        x = pred; labels = ftl; partial = pred_part; Tlen = U; splits = SP;
        b = idx / SP; s = idx % SP;
    }
    int len = Tlen / splits;          // pow2/pow2 -> exact; len <= 256
    int t0 = s * len;
    int tx = threadIdx.x & 127;
    int ty = threadIdx.x >> 7;

    __shared__ int lab[256];
    const int* labg = labels + (size_t)b * Tlen + t0;
    for (int i = threadIdx.x; i < len; i += 256) lab[i] = labg[i];
    __syncthreads();

    const float4* x4 = (const float4*)x + ((size_t)b * Tlen + t0) * D4 + tx;
    float4 acc[C_CLS];
#pragma unroll
    for (int k = 0; k < C_CLS; k++) acc[k] = make_float4(0.f, 0.f, 0.f, 0.f);

    for (int t = ty; t < len; t += 2) {
        float4 v = x4[(size_t)t * D4];
        int c = lab[t];               // wave-uniform LDS broadcast
#pragma unroll
        for (int k = 0; k < C_CLS; k++) {
            float m = (c == k) ? 1.0f : 0.0f;
            acc[k].x = fmaf(v.x, m, acc[k].x);
            acc[k].y = fmaf(v.y, m, acc[k].y);
            acc[k].z = fmaf(v.z, m, acc[k].z);
            acc[k].w = fmaf(v.w, m, acc[k].w);
        }
    }

    __shared__ float4 cbuf[C_CLS][D4];
    if (ty == 1) {
#pragma unroll
        for (int k = 0; k < C_CLS; k++) cbuf[k][tx] = acc[k];
    }
    __syncthreads();
    if (ty == 0) {
        float4* out = (float4*)partial + (size_t)(b * splits + s) * C_CLS * D4 + tx;
#pragma unroll
        for (int k = 0; k < C_CLS; k++) {
            float4 o = acc[k], p = cbuf[k][tx];
            o.x += p.x; o.y += p.y; o.z += p.z; o.w += p.w;
            out[(size_t)k * D4] = o;
        }
    }
}

// ---------------------------------------------------------------------------
// Block-wide sum over 256 threads (wave64 shuffles + LDS across 4 waves).
// ---------------------------------------------------------------------------
__device__ __forceinline__ float blockReduceSum256(float v) {
    __shared__ float red[4];
#pragma unroll
    for (int off = 32; off > 0; off >>= 1) v += __shfl_down(v, off);
    int wid = threadIdx.x >> 6, lane = threadIdx.x & 63;
    __syncthreads();                  // protect red from a previous call
    if (lane == 0) red[wid] = v;
    __syncthreads();
    return red[0] + red[1] + red[2] + red[3];
}

// ---------------------------------------------------------------------------
// Kernel 3: per-(b,c) row: reduce partials -> mean -> concat -> LayerNorm ->
// 4-logit matvec -> log_softmax -> diagonal entry logp[b,c,c].
// grid (B, C_CLS), block 256.
// ---------------------------------------------------------------------------
__global__ void finalize_kernel(const float* __restrict__ enc_part,
                                const float* __restrict__ pred_part,
                                const float* __restrict__ cnt,
                                const float* __restrict__ norm_w, const float* __restrict__ norm_b,
                                const float* __restrict__ head_w, const float* __restrict__ head_b,
                                float* __restrict__ diag, int B, int SE, int SP) {
    int b = blockIdx.x;
    int c = blockIdx.y;
    __shared__ float feat[DFEAT];
    float cnt_e = fmaxf(cnt[((size_t)0 * B + b) * C_CLS + c], 1.0f);
    float cnt_p = fmaxf(cnt[((size_t)1 * B + b) * C_CLS + c], 1.0f);

    for (int d = threadIdx.x; d < D_HALF; d += 256) {
        float s = 0.f;
        for (int sp = 0; sp < SE; sp++)
            s += enc_part[((size_t)(b * SE + sp) * C_CLS + c) * D_HALF + d];
        feat[d] = s / cnt_e;
    }
    for (int d = threadIdx.x; d < D_HALF; d += 256) {
        float s = 0.f;
        for (int sp = 0; sp < SP; sp++)
            s += pred_part[((size_t)(b * SP + sp) * C_CLS + c) * D_HALF + d];
        feat[D_HALF + d] = s / cnt_p;
    }
    __syncthreads();

    float lsum = 0.f;
    for (int d = threadIdx.x; d < DFEAT; d += 256) lsum += feat[d];
    float mu = blockReduceSum256(lsum) * (1.0f / DFEAT);

    float lvar = 0.f;
    for (int d = threadIdx.x; d < DFEAT; d += 256) {
        float t = feat[d] - mu;
        lvar = fmaf(t, t, lvar);
    }
    float var = blockReduceSum256(lvar) * (1.0f / DFEAT);
    float rstd = rsqrtf(var + 1e-5f);

    float part[C_CLS] = {0.f, 0.f, 0.f, 0.f};
    for (int d = threadIdx.x; d < DFEAT; d += 256) {
        float fn = (feat[d] - mu) * rstd * norm_w[d] + norm_b[d];
#pragma unroll
        for (int n = 0; n < C_CLS; n++)
            part[n] = fmaf(fn, head_w[(size_t)n * DFEAT + d], part[n]);
    }
    float logits[C_CLS];
#pragma unroll
    for (int n = 0; n < C_CLS; n++)
        logits[n] = blockReduceSum256(part[n]) + head_b[n];

    if (threadIdx.x == 0) {
        float m = fmaxf(fmaxf(logits[0], logits[1]), fmaxf(logits[2], logits[3]));
        float se = 0.f;
#pragma unroll
        for (int n = 0; n < C_CLS; n++) se += expf(logits[n] - m);
        float lse = m + logf(se);
        diag[b * C_CLS + c] = logits[c] - lse;   // logp[b,c,c]
    }
}

// ---------------------------------------------------------------------------
// Kernel 4: gather sel via the actual label input, reduce, write loss.
// ---------------------------------------------------------------------------
__global__ void loss_kernel(const float* __restrict__ diag, const int* __restrict__ label,
                            float* __restrict__ out, int B) {
    int i = threadIdx.x;
    float v = 0.f;
    if (i < B * C_CLS) {
        int b = i / C_CLS;
        int j = label[i];                 // label[b][l]
        v = diag[b * C_CLS + j];          // logp[b, j, j]
    }
#pragma unroll
    for (int off = 32; off > 0; off >>= 1) v += __shfl_down(v, off);
    __shared__ float red[2];
    int wid = i >> 6, lane = i & 63;
    if (lane == 0) red[wid] = v;
    __syncthreads();
    if (i == 0) out[0] = -(red[0] + red[1]) / (float)(B * C_CLS);
}

// ---------------------------------------------------------------------------
extern "C" void kernel_launch(void* const* d_in, const int* in_sizes, int n_in,
                              void* d_out, int out_size, void* d_ws, size_t ws_size,
                              hipStream_t stream) {
    const float* enc_out      = (const float*)d_in[0];
    const float* pred_out     = (const float*)d_in[1];
    const int*   frame_label  = (const int*)d_in[2];
    const int*   frame_tlabel = (const int*)d_in[3];
    const int*   label        = (const int*)d_in[4];
    const float* norm_w       = (const float*)d_in[5];
    const float* norm_b       = (const float*)d_in[6];
    const float* head_w       = (const float*)d_in[7];
    const float* head_b       = (const float*)d_in[8];
    float* out = (float*)d_out;

    const int B = BB, T = 4096, U = 1024;
    int SE = 64, SP = 32;     // 2048 + 1024 blocks -> full occupancy queue
    auto need = [&](int se, int sp) -> size_t {
        return ((size_t)B * se * C_CLS * D_HALF + (size_t)B * sp * C_CLS * D_HALF
                + 2 * B * C_CLS + B * C_CLS) * sizeof(float);
    };
    while (need(SE, SP) > ws_size && SE > 16) { SE >>= 1; if (SP > 4) SP >>= 1; }

    float* ws        = (float*)d_ws;
    float* enc_part  = ws;
    float* pred_part = enc_part + (size_t)B * SE * C_CLS * D_HALF;
    float* cnt       = pred_part + (size_t)B * SP * C_CLS * D_HALF;
    float* diag      = cnt + 2 * B * C_CLS;

    count_kernel<<<dim3(B, 2), 256, 0, stream>>>(frame_label, frame_tlabel, T, U, cnt);
    masked_sum_fused<<<B * SE + B * SP, 256, 0, stream>>>(enc_out, pred_out,
                                                          frame_label, frame_tlabel,
                                                          enc_part, pred_part, T, U, SE, SP);
    finalize_kernel<<<dim3(B, C_CLS), 256, 0, stream>>>(enc_part, pred_part, cnt,
                                                        norm_w, norm_b, head_w, head_b,
                                                        diag, B, SE, SP);
    loss_kernel<<<1, 128, 0, stream>>>(diag, label, out, B);
}

// Round 3
// 436.846 us; speedup vs baseline: 1.0967x; 1.0967x over previous
//
#include <hip/hip_runtime.h>
#include <math.h>

#define C_CLS 4
#define D_HALF 512
#define D4 128      // D_HALF / 4
#define DFEAT 1024
#define BB 32

typedef float f4 __attribute__((ext_vector_type(4)));

// ---------------------------------------------------------------------------
// Kernel A: fused masked segmented sums over enc (B*SE blocks) + pred
// (B*SP blocks), 1-D grid, block 256. tx = float4 column (0..127), ty = t
// parity. partial layout: [B][splits][C_CLS][D_HALF] floats.
// Block 0 also zeroes out[0] (kernel B accumulates the loss there with
// atomics; ordering guaranteed by the A->B launch dependency).
// Nontemporal loads: the 320 MB stream is read exactly once.
// ---------------------------------------------------------------------------
__global__ void masked_sum_fused(const float* __restrict__ enc, const float* __restrict__ pred,
                                 const int* __restrict__ fl, const int* __restrict__ ftl,
                                 float* __restrict__ enc_part, float* __restrict__ pred_part,
                                 float* __restrict__ out,
                                 int T, int U, int SE, int SP) {
    int bid = blockIdx.x;
    if (bid == 0 && threadIdx.x == 0) out[0] = 0.0f;

    const float* x; const int* labels; float* partial;
    int Tlen, splits, b, s;
    if (bid < BB * SE) {
        x = enc; labels = fl; partial = enc_part; Tlen = T; splits = SE;
        b = bid / SE; s = bid % SE;
    } else {
        int idx = bid - BB * SE;
        x = pred; labels = ftl; partial = pred_part; Tlen = U; splits = SP;
        b = idx / SP; s = idx % SP;
    }
    int len = Tlen / splits;          // pow2/pow2 -> exact; len in {32,64..256}
    int t0 = s * len;
    int tx = threadIdx.x & 127;
    int ty = threadIdx.x >> 7;

    __shared__ int lab[256];
    const int* labg = labels + (size_t)b * Tlen + t0;
    for (int i = threadIdx.x; i < len; i += 256) lab[i] = labg[i];
    __syncthreads();

    const f4* x4 = (const f4*)x + ((size_t)b * Tlen + t0) * D4 + tx;
    f4 acc[C_CLS];
#pragma unroll
    for (int k = 0; k < C_CLS; k++) acc[k] = (f4){0.f, 0.f, 0.f, 0.f};

    // t-loop, parity-split across ty, manually unrolled x2 so two 1 KB/wave
    // loads are in flight before the dependent FMAs.
    int t = ty;
    for (; t + 2 < len; t += 4) {
        f4 v0 = __builtin_nontemporal_load(&x4[(size_t)t * D4]);
        f4 v1 = __builtin_nontemporal_load(&x4[(size_t)(t + 2) * D4]);
        int c0 = lab[t], c1 = lab[t + 2];
#pragma unroll
        for (int k = 0; k < C_CLS; k++) {
            acc[k] += v0 * (float)(c0 == k);
            acc[k] += v1 * (float)(c1 == k);
        }
    }
    for (; t < len; t += 2) {
        f4 v = __builtin_nontemporal_load(&x4[(size_t)t * D4]);
        int c = lab[t];
#pragma unroll
        for (int k = 0; k < C_CLS; k++) acc[k] += v * (float)(c == k);
    }

    __shared__ f4 cbuf[C_CLS][D4];
    if (ty == 1) {
#pragma unroll
        for (int k = 0; k < C_CLS; k++) cbuf[k][tx] = acc[k];
    }
    __syncthreads();
    if (ty == 0) {
        f4* o4 = (f4*)partial + (size_t)(b * splits + s) * C_CLS * D4 + tx;
#pragma unroll
        for (int k = 0; k < C_CLS; k++)
            o4[(size_t)k * D4] = acc[k] + cbuf[k][tx];
    }
}

// ---------------------------------------------------------------------------
// Block-wide sum over 256 threads (wave64 shuffles + LDS across 4 waves).
// ---------------------------------------------------------------------------
__device__ __forceinline__ float blockReduceSum256(float v) {
    __shared__ float red[4];
#pragma unroll
    for (int off = 32; off > 0; off >>= 1) v += __shfl_down(v, off);
    int wid = threadIdx.x >> 6, lane = threadIdx.x & 63;
    __syncthreads();                  // protect red from a previous call
    if (lane == 0) red[wid] = v;
    __syncthreads();
    return red[0] + red[1] + red[2] + red[3];
}

// ---------------------------------------------------------------------------
// Kernel B: per-(b,c) row: label counts (rescanned from the 16/4 KB label
// rows) -> reduce partials -> mean -> concat -> LayerNorm -> 4-logit matvec
// -> log_softmax diag -> loss contribution via atomicAdd into out[0].
// grid (B, C_CLS), block 256.
// ---------------------------------------------------------------------------
__global__ void finalize_loss_kernel(const float* __restrict__ enc_part,
                                     const float* __restrict__ pred_part,
                                     const int* __restrict__ fl, const int* __restrict__ ftl,
                                     const int* __restrict__ label,
                                     const float* __restrict__ norm_w, const float* __restrict__ norm_b,
                                     const float* __restrict__ head_w, const float* __restrict__ head_b,
                                     float* __restrict__ out,
                                     int T, int U, int B, int SE, int SP) {
    int b = blockIdx.x;
    int c = blockIdx.y;

    // counts for class c in this batch row
    int ce = 0, cp = 0;
    {
        const int* p = fl + (size_t)b * T;
        for (int i = threadIdx.x; i < T; i += 256) ce += (p[i] == c);
        const int* q = ftl + (size_t)b * U;
        for (int i = threadIdx.x; i < U; i += 256) cp += (q[i] == c);
    }
    float cnt_e = fmaxf(blockReduceSum256((float)ce), 1.0f);
    float cnt_p = fmaxf(blockReduceSum256((float)cp), 1.0f);

    __shared__ float feat[DFEAT];
    for (int d = threadIdx.x; d < D_HALF; d += 256) {
        float s = 0.f;
        for (int sp = 0; sp < SE; sp++)
            s += enc_part[((size_t)(b * SE + sp) * C_CLS + c) * D_HALF + d];
        feat[d] = s / cnt_e;
    }
    for (int d = threadIdx.x; d < D_HALF; d += 256) {
        float s = 0.f;
        for (int sp = 0; sp < SP; sp++)
            s += pred_part[((size_t)(b * SP + sp) * C_CLS + c) * D_HALF + d];
        feat[D_HALF + d] = s / cnt_p;
    }
    __syncthreads();

    float lsum = 0.f;
    for (int d = threadIdx.x; d < DFEAT; d += 256) lsum += feat[d];
    float mu = blockReduceSum256(lsum) * (1.0f / DFEAT);

    float lvar = 0.f;
    for (int d = threadIdx.x; d < DFEAT; d += 256) {
        float t = feat[d] - mu;
        lvar = fmaf(t, t, lvar);
    }
    float var = blockReduceSum256(lvar) * (1.0f / DFEAT);
    float rstd = rsqrtf(var + 1e-5f);

    float part[C_CLS] = {0.f, 0.f, 0.f, 0.f};
    for (int d = threadIdx.x; d < DFEAT; d += 256) {
        float fn = (feat[d] - mu) * rstd * norm_w[d] + norm_b[d];
#pragma unroll
        for (int n = 0; n < C_CLS; n++)
            part[n] = fmaf(fn, head_w[(size_t)n * DFEAT + d], part[n]);
    }
    float logits[C_CLS];
#pragma unroll
    for (int n = 0; n < C_CLS; n++)
        logits[n] = blockReduceSum256(part[n]) + head_b[n];

    if (threadIdx.x == 0) {
        float m = fmaxf(fmaxf(logits[0], logits[1]), fmaxf(logits[2], logits[3]));
        float se = 0.f;
#pragma unroll
        for (int n = 0; n < C_CLS; n++) se += expf(logits[n] - m);
        float lp = logits[c] - (m + logf(se));   // logp[b,c,c]
        // occurrences of class c in label[b, :]
        int occ = 0;
#pragma unroll
        for (int l = 0; l < C_CLS; l++) occ += (label[b * C_CLS + l] == c);
        if (occ)
            atomicAdd(out, -lp * (float)occ * (1.0f / (BB * C_CLS)));
    }
}

// ---------------------------------------------------------------------------
extern "C" void kernel_launch(void* const* d_in, const int* in_sizes, int n_in,
                              void* d_out, int out_size, void* d_ws, size_t ws_size,
                              hipStream_t stream) {
    const float* enc_out      = (const float*)d_in[0];
    const float* pred_out     = (const float*)d_in[1];
    const int*   frame_label  = (const int*)d_in[2];
    const int*   frame_tlabel = (const int*)d_in[3];
    const int*   label        = (const int*)d_in[4];
    const float* norm_w       = (const float*)d_in[5];
    const float* norm_b       = (const float*)d_in[6];
    const float* head_w       = (const float*)d_in[7];
    const float* head_b       = (const float*)d_in[8];
    float* out = (float*)d_out;

    const int B = BB, T = 4096, U = 1024;
    int SE = 64, SP = 32;     // 2048 + 1024 blocks
    auto need = [&](int se, int sp) -> size_t {
        return ((size_t)B * se * C_CLS * D_HALF + (size_t)B * sp * C_CLS * D_HALF)
               * sizeof(float);
    };
    while (need(SE, SP) > ws_size && SE > 16) { SE >>= 1; if (SP > 4) SP >>= 1; }

    float* enc_part  = (float*)d_ws;
    float* pred_part = enc_part + (size_t)B * SE * C_CLS * D_HALF;

    masked_sum_fused<<<B * SE + B * SP, 256, 0, stream>>>(enc_out, pred_out,
                                                          frame_label, frame_tlabel,
                                                          enc_part, pred_part, out,
                                                          T, U, SE, SP);
    finalize_loss_kernel<<<dim3(B, C_CLS), 256, 0, stream>>>(enc_part, pred_part,
                                                             frame_label, frame_tlabel, label,
                                                             norm_w, norm_b, head_w, head_b,
                                                             out, T, U, B, SE, SP);
}